// Round 15
// baseline (237.362 us; speedup 1.0000x reference)
//
#include <hip/hip_runtime.h>
#include <hip/hip_bf16.h>

typedef __attribute__((ext_vector_type(8))) short bf16x8;
typedef __attribute__((ext_vector_type(4))) float f32x4;

#define MFMA_BF16(a, b, c) __builtin_amdgcn_mfma_f32_16x16x32_bf16((a), (b), (c), 0, 0, 0)

#define E_DIM 384
#define T_SEQ 256
#define B_BATCH 128
#define H_HEADS 6
#define D_HEAD 64
#define NROWS (B_BATCH * T_SEQ)   // 32768
#define FF_DIM (4 * E_DIM)        // 1536
#define QKV_LD 1152               // 3*E

__device__ __forceinline__ void load_lds16(const __hip_bfloat16* g, __hip_bfloat16* l) {
    __builtin_amdgcn_global_load_lds(
        (const __attribute__((address_space(1))) void*)g,
        (__attribute__((address_space(3))) void*)l, 16, 0, 0);
}

__device__ __forceinline__ float to_f(float x) { return x; }
__device__ __forceinline__ float to_f(__hip_bfloat16 x) { return __bfloat162float(x); }

// ---------------------------------------------------------------------------
// All weight transposes + casts in one launch.
// ---------------------------------------------------------------------------
__global__ void tcast_all_kernel(const float* __restrict__ wq, const float* __restrict__ wk,
                                 const float* __restrict__ wv, const float* __restrict__ wp,
                                 const float* __restrict__ w1, const float* __restrict__ w2,
                                 __hip_bfloat16* __restrict__ wqkvT, __hip_bfloat16* __restrict__ wpT,
                                 __hip_bfloat16* __restrict__ w1T, __hip_bfloat16* __restrict__ w2T) {
    const int WE = E_DIM * E_DIM;   // 147456
    const int FE = E_DIM * FF_DIM;  // 589824
    int idx = blockIdx.x * 256 + threadIdx.x;
    if (idx < 3 * WE) {
        int seg = idx / WE, j = idx - seg * WE;
        const float* W = seg == 0 ? wq : (seg == 1 ? wk : wv);
        int k = j / E_DIM, n = j - k * E_DIM;
        wqkvT[(size_t)seg * WE + (size_t)n * E_DIM + k] = __float2bfloat16(W[j]);
    } else if (idx < 4 * WE) {
        int j = idx - 3 * WE;
        int k = j / E_DIM, n = j - k * E_DIM;
        wpT[(size_t)n * E_DIM + k] = __float2bfloat16(wp[j]);
    } else if (idx < 4 * WE + FE) {
        int j = idx - 4 * WE;
        int k = j / FF_DIM, n = j - k * FF_DIM;
        w1T[(size_t)n * E_DIM + k] = __float2bfloat16(w1[j]);
    } else {
        int j = idx - 4 * WE - FE;
        int k = j / E_DIM, n = j - k * E_DIM;
        w2T[(size_t)n * FF_DIM + k] = __float2bfloat16(w2[j]);
    }
}

// ---------------------------------------------------------------------------
// LayerNorm: x[rows][384] (f32 or bf16) -> out[rows][384] bf16. One wave/row.
// ---------------------------------------------------------------------------
template <typename TI>
__global__ __launch_bounds__(256) void ln_kernel(const TI* __restrict__ x,
                                                 const float* __restrict__ g,
                                                 const float* __restrict__ bta,
                                                 __hip_bfloat16* __restrict__ out) {
    int row = blockIdx.x * 4 + (threadIdx.x >> 6);
    int lane = threadIdx.x & 63;
    const TI* xr = x + (size_t)row * E_DIM;
    float vals[6];
    float s = 0.f;
#pragma unroll
    for (int i = 0; i < 3; i++) {
        int c = i * 128 + 2 * lane;
        if constexpr (sizeof(TI) == 4) {
            float2 v = *reinterpret_cast<const float2*>(&xr[c]);
            vals[2 * i] = v.x;
            vals[2 * i + 1] = v.y;
        } else {
            ushort2 u = *reinterpret_cast<const ushort2*>(&xr[c]);
            union { unsigned short us; __hip_bfloat16 h; } a, b2;
            a.us = u.x; b2.us = u.y;
            vals[2 * i] = __bfloat162float(a.h);
            vals[2 * i + 1] = __bfloat162float(b2.h);
        }
        s += vals[2 * i] + vals[2 * i + 1];
    }
#pragma unroll
    for (int off = 1; off < 64; off <<= 1) s += __shfl_xor(s, off, 64);
    float mu = s * (1.f / E_DIM);
    float vv = 0.f;
#pragma unroll
    for (int i = 0; i < 6; i++) {
        float d = vals[i] - mu;
        vv += d * d;
    }
#pragma unroll
    for (int off = 1; off < 64; off <<= 1) vv += __shfl_xor(vv, off, 64);
    float rstd = rsqrtf(vv * (1.f / E_DIM) + 1e-5f);
#pragma unroll
    for (int i = 0; i < 3; i++) {
        int c = i * 128 + 2 * lane;
        float2 gv = *reinterpret_cast<const float2*>(&g[c]);
        float2 bv = *reinterpret_cast<const float2*>(&bta[c]);
        union { ushort2 u; struct { __hip_bfloat16 a, b; } h; } o2;
        o2.h.a = __float2bfloat16((vals[2 * i] - mu) * rstd * gv.x + bv.x);
        o2.h.b = __float2bfloat16((vals[2 * i + 1] - mu) * rstd * gv.y + bv.y);
        *reinterpret_cast<ushort2*>(&out[(size_t)row * E_DIM + c]) = o2.u;
    }
}

// ---------------------------------------------------------------------------
// Pipelined GEMM (round-9 structure): C = A[M][K] @ BT[N][K]^T, bf16, f32 acc.
// NW=8: BM=256, 512 thr, 72KB LDS, 2 blocks/CU. NW=4: BM=128, 256 thr, 48KB,
// 3 blocks/CU. BN=128, BK=32, triple-buffered, counted vmcnt, raw s_barrier,
// T5 setprio. Paired-row 128B-line LDS swizzle (zero bank conflicts).
// EPI: 0 = bf16 out; 2 = +bias relu -> bf16; 3 = +bias + f32 resid -> bf16;
//      4 = +bias + bf16 resid -> f32 out.
// ---------------------------------------------------------------------------
template <int EPI, int NW>
__global__ __launch_bounds__(NW * 64, NW == 8 ? 4 : 3) void gemm_kernel(
    const __hip_bfloat16* __restrict__ A, const __hip_bfloat16* __restrict__ BT,
    const float* __restrict__ bias, const void* __restrict__ resid,
    void* __restrict__ outp, int M, int N, int K) {
    constexpr int BM = NW * 32;
    constexpr int T = NW * 64;
    constexpr int BUF = (BM + 128) * 32;
    __shared__ __hip_bfloat16 lds[3 * BUF];
    const int t = threadIdx.x;
    const int w = t >> 6, lane = t & 63;
    const int l16 = lane & 15, lhi = lane >> 4;
    const int wm = w >> 1, wn = w & 1;

    const int nwg = gridDim.x;
    const int bid = blockIdx.x;
    const int cpx = nwg >> 3;
    const int swz = (bid & 7) * cpx + (bid >> 3);
    const int nb = N >> 7;
    const int m0 = (swz / nb) * BM;
    const int n0 = (swz % nb) * 128;

    const int ql = (t & 7) ^ ((t >> 3) & 7);
    const int sr = 2 * (t >> 3) + (ql >> 2);
    const int scol = (ql & 3) * 8;
    const __hip_bfloat16* pa0 = A + (size_t)(m0 + sr) * K + scol;
    const __hip_bfloat16* pa1 = pa0 + (size_t)(T / 4) * K;
    const __hip_bfloat16* pb0 = BT + (size_t)(n0 + sr) * K + scol;
    const __hip_bfloat16* pb1 = pb0 + (size_t)(T / 4) * K;
    const int dstA = t * 8;

    int aoff[4], boff[4];
#pragma unroll
    for (int mr = 0; mr < 4; mr++) {
        int R = wm * 64 + mr * 16 + l16;
        int L = R >> 1;
        int q = (((R & 1) << 2) | lhi) ^ (L & 7);
        aoff[mr] = L * 64 + q * 8;
    }
#pragma unroll
    for (int nr = 0; nr < 4; nr++) {
        int R = wn * 64 + nr * 16 + l16;
        int L = R >> 1;
        int q = (((R & 1) << 2) | lhi) ^ (L & 7);
        boff[nr] = BM * 32 + L * 64 + q * 8;
    }

    f32x4 acc[4][4] = {};
    const int nk = K >> 5;

#define STAGE(sbuf)                                                           \
    {                                                                         \
        __hip_bfloat16* sb_ = &lds[(sbuf) * BUF];                             \
        load_lds16(pa0, sb_ + dstA);                                          \
        load_lds16(pa1, sb_ + T * 8 + dstA);                                  \
        load_lds16(pb0, sb_ + BM * 32 + dstA);                                \
        if constexpr (NW == 4) load_lds16(pb1, sb_ + BM * 32 + T * 8 + dstA); \
        pa0 += 32;                                                            \
        pa1 += 32;                                                            \
        pb0 += 32;                                                            \
        if constexpr (NW == 4) pb1 += 32;                                     \
    }

    STAGE(0);
    STAGE(1);
    int rb = 0, sbx = 2;

    for (int kt = 0; kt < nk; kt++) {
        if (kt + 1 < nk) {
            if constexpr (NW == 8) asm volatile("s_waitcnt vmcnt(3)" ::: "memory");
            else                   asm volatile("s_waitcnt vmcnt(4)" ::: "memory");
        } else {
            asm volatile("s_waitcnt vmcnt(0)" ::: "memory");
        }
        __builtin_amdgcn_s_barrier();
        __builtin_amdgcn_sched_barrier(0);
        if (kt + 2 < nk) STAGE(sbx);
        const __hip_bfloat16* base = &lds[rb * BUF];
        bf16x8 af[4], bg[4];
#pragma unroll
        for (int mr = 0; mr < 4; mr++)
            af[mr] = *reinterpret_cast<const bf16x8*>(base + aoff[mr]);
#pragma unroll
        for (int nr = 0; nr < 4; nr++)
            bg[nr] = *reinterpret_cast<const bf16x8*>(base + boff[nr]);
        __builtin_amdgcn_s_setprio(1);
#pragma unroll
        for (int mr = 0; mr < 4; mr++)
#pragma unroll
            for (int nr = 0; nr < 4; nr++)
                acc[mr][nr] = MFMA_BF16(af[mr], bg[nr], acc[mr][nr]);
        __builtin_amdgcn_s_setprio(0);
        rb = rb == 2 ? 0 : rb + 1;
        sbx = sbx == 2 ? 0 : sbx + 1;
    }
#undef STAGE

    __hip_bfloat16* outb = (__hip_bfloat16*)outp;
    float* outf = (float*)outp;
#pragma unroll
    for (int mr = 0; mr < 4; mr++) {
#pragma unroll
        for (int nr = 0; nr < 4; nr++) {
            const int col = n0 + wn * 64 + nr * 16 + l16;
#pragma unroll
            for (int r = 0; r < 4; r++) {
                const int row = m0 + wm * 64 + mr * 16 + lhi * 4 + r;
                const size_t off = (size_t)row * N + col;
                float v = acc[mr][nr][r];
                if (EPI == 0) {
                    outb[off] = __float2bfloat16(v);
                } else if (EPI == 2) {
                    v += bias[col];
                    outb[off] = __float2bfloat16(v > 0.f ? v : 0.f);
                } else if (EPI == 3) {
                    v += bias[col] + ((const float*)resid)[off];
                    outb[off] = __float2bfloat16(v);
                } else {  // EPI == 4
                    v += bias[col] + to_f(((const __hip_bfloat16*)resid)[off]);
                    outf[off] = v;
                }
            }
        }
    }
}

// ---------------------------------------------------------------------------
// Causal attention, one block per (b,h), 256 thr = 4 waves, 2 blocks/CU.
// Wave w processes Q chunks {w, 7-w}. SWAPPED QK^T: s = MFMA(K, Q) so the
// lane holds 16 score values for ONE q-row -> in-lane softmax + 2 shfl_xor.
// ---------------------------------------------------------------------------
__global__ __launch_bounds__(256, 2) void attn_kernel(
    const __hip_bfloat16* __restrict__ qkv, __hip_bfloat16* __restrict__ o) {
    __shared__ __hip_bfloat16 Ks[T_SEQ * 64];    // 32 KB
    __shared__ __hip_bfloat16 VTs[64 * 256];     // 32 KB
    __shared__ __hip_bfloat16 Ps[4 * 2048];      // 16 KB

    const int bh = blockIdx.x;
    const int b = bh / H_HEADS, h = bh - b * H_HEADS;
    const int t = threadIdx.x;
    const int w = t >> 6, lane = t & 63;
    const int l16 = lane & 15, lhi = lane >> 4;
    const int l8 = l16 & 7;
    const size_t rbase = (size_t)b * T_SEQ;
    const int qoff = h * D_HEAD, koff = E_DIM + h * D_HEAD, voff = 2 * E_DIM + h * D_HEAD;
    const float qscale = 0.051031036307982884f * 1.4426950408889634f;

#pragma unroll
    for (int i = 0; i < 8; i++) {
        int idx = i * 256 + t;
        int r = idx >> 3;
        int c8 = idx & 7;
        load_lds16(qkv + (rbase + r) * QKV_LD + koff + ((c8 ^ (r & 7)) << 3),
                   &Ks[idx * 8]);
    }
#pragma unroll
    for (int i = 0; i < 8; i++) {
        int idx = i * 256 + t;
        int r = idx >> 3, d0 = (idx & 7) * 8;
        uint4 val = *reinterpret_cast<const uint4*>(qkv + (rbase + r) * QKV_LD + voff + d0);
        const __hip_bfloat16* p8 = reinterpret_cast<const __hip_bfloat16*>(&val);
        int slot = r >> 3, rin = r & 7;
#pragma unroll
        for (int j = 0; j < 8; j++) {
            int d = d0 + j;
            VTs[d * 256 + ((slot ^ (d & 7)) << 3) + rin] = p8[j];
        }
    }
    __syncthreads();

#pragma unroll
    for (int cp = 0; cp < 2; cp++) {
        const int c = cp ? 7 - w : w;
        bf16x8 qf[2][2];
#pragma unroll
        for (int mr = 0; mr < 2; mr++)
#pragma unroll
            for (int kk = 0; kk < 2; kk++)
                qf[mr][kk] = *reinterpret_cast<const bf16x8*>(
                    qkv + (rbase + c * 32 + mr * 16 + l16) * QKV_LD + qoff + kk * 32 + lhi * 8);

        float mstate[2] = {-1e30f, -1e30f};
        float lstate[2] = {0.f, 0.f};
        f32x4 oacc[2][4] = {};

        const int njt = (c >> 1) + 1;
        for (int jt = 0; jt < njt; jt++) {
            const bool diag = (jt == (c >> 1));
            f32x4 s[2][4] = {};
#pragma unroll
            for (int kk = 0; kk < 2; kk++) {
                bf16x8 kf[4];
#pragma unroll
                for (int nr = 0; nr < 4; nr++) {
                    int R = jt * 64 + nr * 16 + l16;
                    kf[nr] = *reinterpret_cast<const bf16x8*>(
                        &Ks[R * 64 + (((kk << 2) + lhi) ^ l8) * 8]);
                }
#pragma unroll
                for (int mr = 0; mr < 2; mr++)
#pragma unroll
                    for (int nr = 0; nr < 4; nr++)
                        s[mr][nr] = MFMA_BF16(kf[nr], qf[mr][kk], s[mr][nr]);
            }
#pragma unroll
            for (int mr = 0; mr < 2; mr++) {
                const int qrow = c * 32 + mr * 16 + l16;
                float pv[4][4];
                float mx = -1e30f;
#pragma unroll
                for (int nr = 0; nr < 4; nr++)
#pragma unroll
                    for (int r = 0; r < 4; r++) {
                        int kcol = jt * 64 + nr * 16 + lhi * 4 + r;
                        float val = s[mr][nr][r] * qscale;
                        if (diag && kcol > qrow) val = -1e30f;
                        pv[nr][r] = val;
                        mx = fmaxf(mx, val);
                    }
                mx = fmaxf(mx, __shfl_xor(mx, 16, 64));
                mx = fmaxf(mx, __shfl_xor(mx, 32, 64));
                float mold = mstate[mr];
                float mnew = fmaxf(mold, mx);
                float corr = exp2f(mold - mnew);
                float psum = 0.f;
#pragma unroll
                for (int nr = 0; nr < 4; nr++)
#pragma unroll
                    for (int r = 0; r < 4; r++) {
                        float p = exp2f(pv[nr][r] - mnew);
                        pv[nr][r] = p;
                        psum += p;
                    }
                psum += __shfl_xor(psum, 16, 64);
                psum += __shfl_xor(psum, 32, 64);
                lstate[mr] = lstate[mr] * corr + psum;
                mstate[mr] = mnew;
#pragma unroll
                for (int r = 0; r < 4; r++) {
                    float cT = __shfl(corr, lhi * 4 + r, 64);
#pragma unroll
                    for (int dr = 0; dr < 4; dr++) oacc[mr][dr][r] *= cT;
                }
#pragma unroll
                for (int nr = 0; nr < 4; nr++)
#pragma unroll
                    for (int r = 0; r < 4; r++) {
                        int q = mr * 16 + l16;
                        int kc = nr * 16 + lhi * 4 + r;
                        Ps[w * 2048 + q * 64 + (((kc >> 3) ^ (q & 7)) << 3) + (kc & 7)] =
                            __float2bfloat16(pv[nr][r]);
                    }
            }
#pragma unroll
            for (int kk = 0; kk < 2; kk++) {
                bf16x8 pa[2], vbf[4];
#pragma unroll
                for (int mr = 0; mr < 2; mr++) {
                    int row = mr * 16 + l16;
                    pa[mr] = *reinterpret_cast<const bf16x8*>(
                        &Ps[w * 2048 + row * 64 + (((kk << 2) + lhi) ^ l8) * 8]);
                }
#pragma unroll
                for (int dr = 0; dr < 4; dr++) {
                    int d = dr * 16 + l16;
                    int slot = (jt << 3) + (kk << 2) + lhi;
                    vbf[dr] = *reinterpret_cast<const bf16x8*>(
                        &VTs[d * 256 + ((slot ^ l8) << 3)]);
                }
#pragma unroll
                for (int mr = 0; mr < 2; mr++)
#pragma unroll
                    for (int dr = 0; dr < 4; dr++)
                        oacc[mr][dr] = MFMA_BF16(pa[mr], vbf[dr], oacc[mr][dr]);
            }
        }

#pragma unroll
        for (int mr = 0; mr < 2; mr++) {
            float rl = 1.f / lstate[mr];
#pragma unroll
            for (int r = 0; r < 4; r++) {
                float rlT = __shfl(rl, lhi * 4 + r, 64);
                int row = c * 32 + mr * 16 + lhi * 4 + r;
#pragma unroll
                for (int dr = 0; dr < 4; dr++)
                    o[(rbase + row) * E_DIM + h * D_HEAD + dr * 16 + l16] =
                        __float2bfloat16(oacc[mr][dr][r] * rlT);
            }
        }
    }
}

// ---------------------------------------------------------------------------
extern "C" void kernel_launch(void* const* d_in, const int* in_sizes, int n_in,
                              void* d_out, int out_size, void* d_ws, size_t ws_size,
                              hipStream_t stream) {
    const float* x      = (const float*)d_in[0];
    const float* wq     = (const float*)d_in[1];
    const float* wk     = (const float*)d_in[2];
    const float* wv     = (const float*)d_in[3];
    const float* w_proj = (const float*)d_in[4];
    const float* b_proj = (const float*)d_in[5];
    const float* w1     = (const float*)d_in[6];
    const float* b1     = (const float*)d_in[7];
    const float* w2     = (const float*)d_in[8];
    const float* b2     = (const float*)d_in[9];
    const float* g1     = (const float*)d_in[10];
    const float* bt1    = (const float*)d_in[11];
    const float* g2     = (const float*)d_in[12];
    const float* bt2    = (const float*)d_in[13];
    float* out = (float*)d_out;

    char* ws = (char*)d_ws;
    size_t off = 0;
    auto alloc = [&](size_t bytes) {
        void* p = ws + off;
        off += (bytes + 255) & ~(size_t)255;
        return p;
    };
    const size_t wElems = E_DIM * E_DIM;
    const size_t fElems = E_DIM * FF_DIM;
    const size_t actElems = (size_t)NROWS * E_DIM;
    __hip_bfloat16* wqkvT = (__hip_bfloat16*)alloc(3 * wElems * 2);  // [1152][384]
    __hip_bfloat16* wpT   = (__hip_bfloat16*)alloc(wElems * 2);
    __hip_bfloat16* w1T   = (__hip_bfloat16*)alloc(fElems * 2);
    __hip_bfloat16* w2T   = (__hip_bfloat16*)alloc(fElems * 2);
    __hip_bfloat16* lnb   = (__hip_bfloat16*)alloc(actElems * 2);      // ln1 / ln2
    __hip_bfloat16* x2b   = (__hip_bfloat16*)alloc(actElems * 2);      // residual (bf16)
    __hip_bfloat16* qkv   = (__hip_bfloat16*)alloc(3 * actElems * 2);  // [32768][1152]
    __hip_bfloat16* ab    = (__hip_bfloat16*)alloc(actElems * 2);      // attn out
    __hip_bfloat16* h1    = qkv;  // FFN hidden (96MB) reuses qkv+ab space

    // 1) all weights -> bf16 transposed, one launch
    tcast_all_kernel<<<6912, 256, 0, stream>>>(wq, wk, wv, w_proj, w1, w2,
                                               wqkvT, wpT, w1T, w2T);

    // 2) ln1
    ln_kernel<float><<<NROWS / 4, 256, 0, stream>>>(x, g1, bt1, lnb);

    // 3) fused qkv: [32768][1152]  (NW4: grid 2304 = 3.0 exact rounds @ 3/CU)
    gemm_kernel<0, 4><<<(NROWS / 128) * (QKV_LD / 128), 256, 0, stream>>>(
        lnb, wqkvT, nullptr, nullptr, qkv, NROWS, QKV_LD, E_DIM);

    // 4) attention
    attn_kernel<<<B_BATCH * H_HEADS, 256, 0, stream>>>(qkv, ab);

    // 5) x2b = bf16(x + attn @ w_proj + b_proj)
    gemm_kernel<3, 4><<<(NROWS / 128) * (E_DIM / 128), 256, 0, stream>>>(
        ab, wpT, b_proj, x, x2b, NROWS, E_DIM, E_DIM);

    // 6) ln2 (bf16 input)
    ln_kernel<__hip_bfloat16><<<NROWS / 4, 256, 0, stream>>>(x2b, g2, bt2, lnb);

    // 7) h1 = relu(ln2 @ w1 + b1)
    gemm_kernel<2, 8><<<(NROWS / 256) * (FF_DIM / 128), 512, 0, stream>>>(
        lnb, w1T, b1, nullptr, h1, NROWS, FF_DIM, E_DIM);

    // 8) out = x2b + h1 @ w2 + b2  (f32 out)
    gemm_kernel<4, 4><<<(NROWS / 128) * (E_DIM / 128), 256, 0, stream>>>(
        h1, w2T, b2, x2b, out, NROWS, E_DIM, FF_DIM);
}

// Round 16
// 229.190 us; speedup vs baseline: 1.0357x; 1.0357x over previous
//
#include <hip/hip_runtime.h>
#include <hip/hip_bf16.h>

typedef __attribute__((ext_vector_type(8))) short bf16x8;
typedef __attribute__((ext_vector_type(4))) float f32x4;

#define MFMA_BF16(a, b, c) __builtin_amdgcn_mfma_f32_16x16x32_bf16((a), (b), (c), 0, 0, 0)

#define E_DIM 384
#define T_SEQ 256
#define B_BATCH 128
#define H_HEADS 6
#define D_HEAD 64
#define NROWS (B_BATCH * T_SEQ)   // 32768
#define FF_DIM (4 * E_DIM)        // 1536
#define QKV_LD 1152               // 3*E
#define TCAST_BLOCKS 6912

__device__ __forceinline__ void load_lds16(const __hip_bfloat16* g, __hip_bfloat16* l) {
    __builtin_amdgcn_global_load_lds(
        (const __attribute__((address_space(1))) void*)g,
        (__attribute__((address_space(3))) void*)l, 16, 0, 0);
}

__device__ __forceinline__ float to_f(float x) { return x; }
__device__ __forceinline__ float to_f(__hip_bfloat16 x) { return __bfloat162float(x); }

// ---------------------------------------------------------------------------
// Fused prologue: weight transposes/casts AND ln1, one launch.
// Blocks [0, 6912): tcast. Blocks [6912, 6912+8192): ln1 (4 rows/block).
// ---------------------------------------------------------------------------
__global__ __launch_bounds__(256) void prep_kernel(
    const float* __restrict__ x, const float* __restrict__ g1,
    const float* __restrict__ bt1, __hip_bfloat16* __restrict__ lnb,
    const float* __restrict__ wq, const float* __restrict__ wk,
    const float* __restrict__ wv, const float* __restrict__ wp,
    const float* __restrict__ w1, const float* __restrict__ w2,
    __hip_bfloat16* __restrict__ wqkvT, __hip_bfloat16* __restrict__ wpT,
    __hip_bfloat16* __restrict__ w1T, __hip_bfloat16* __restrict__ w2T) {
    const int WE = E_DIM * E_DIM;   // 147456
    const int FE = E_DIM * FF_DIM;  // 589824
    if (blockIdx.x < TCAST_BLOCKS) {
        int idx = blockIdx.x * 256 + threadIdx.x;
        if (idx < 3 * WE) {
            int seg = idx / WE, j = idx - seg * WE;
            const float* W = seg == 0 ? wq : (seg == 1 ? wk : wv);
            int k = j / E_DIM, n = j - k * E_DIM;
            wqkvT[(size_t)seg * WE + (size_t)n * E_DIM + k] = __float2bfloat16(W[j]);
        } else if (idx < 4 * WE) {
            int j = idx - 3 * WE;
            int k = j / E_DIM, n = j - k * E_DIM;
            wpT[(size_t)n * E_DIM + k] = __float2bfloat16(wp[j]);
        } else if (idx < 4 * WE + FE) {
            int j = idx - 4 * WE;
            int k = j / FF_DIM, n = j - k * FF_DIM;
            w1T[(size_t)n * E_DIM + k] = __float2bfloat16(w1[j]);
        } else {
            int j = idx - 4 * WE - FE;
            int k = j / E_DIM, n = j - k * E_DIM;
            w2T[(size_t)n * FF_DIM + k] = __float2bfloat16(w2[j]);
        }
        return;
    }
    // ---- ln1 ----
    int row = (blockIdx.x - TCAST_BLOCKS) * 4 + (threadIdx.x >> 6);
    int lane = threadIdx.x & 63;
    const float* xr = x + (size_t)row * E_DIM;
    float vals[6];
    float s = 0.f;
#pragma unroll
    for (int i = 0; i < 3; i++) {
        int c = i * 128 + 2 * lane;
        float2 v = *reinterpret_cast<const float2*>(&xr[c]);
        vals[2 * i] = v.x;
        vals[2 * i + 1] = v.y;
        s += v.x + v.y;
    }
#pragma unroll
    for (int off = 1; off < 64; off <<= 1) s += __shfl_xor(s, off, 64);
    float mu = s * (1.f / E_DIM);
    float vv = 0.f;
#pragma unroll
    for (int i = 0; i < 6; i++) {
        float d = vals[i] - mu;
        vv += d * d;
    }
#pragma unroll
    for (int off = 1; off < 64; off <<= 1) vv += __shfl_xor(vv, off, 64);
    float rstd = rsqrtf(vv * (1.f / E_DIM) + 1e-5f);
#pragma unroll
    for (int i = 0; i < 3; i++) {
        int c = i * 128 + 2 * lane;
        float2 gv = *reinterpret_cast<const float2*>(&g1[c]);
        float2 bv = *reinterpret_cast<const float2*>(&bt1[c]);
        union { ushort2 u; struct { __hip_bfloat16 a, b; } h; } o2;
        o2.h.a = __float2bfloat16((vals[2 * i] - mu) * rstd * gv.x + bv.x);
        o2.h.b = __float2bfloat16((vals[2 * i + 1] - mu) * rstd * gv.y + bv.y);
        *reinterpret_cast<ushort2*>(&lnb[(size_t)row * E_DIM + c]) = o2.u;
    }
}

// ---------------------------------------------------------------------------
// LayerNorm: x[rows][384] (f32 or bf16) -> out[rows][384] bf16. One wave/row.
// ---------------------------------------------------------------------------
template <typename TI>
__global__ __launch_bounds__(256) void ln_kernel(const TI* __restrict__ x,
                                                 const float* __restrict__ g,
                                                 const float* __restrict__ bta,
                                                 __hip_bfloat16* __restrict__ out) {
    int row = blockIdx.x * 4 + (threadIdx.x >> 6);
    int lane = threadIdx.x & 63;
    const TI* xr = x + (size_t)row * E_DIM;
    float vals[6];
    float s = 0.f;
#pragma unroll
    for (int i = 0; i < 3; i++) {
        int c = i * 128 + 2 * lane;
        if constexpr (sizeof(TI) == 4) {
            float2 v = *reinterpret_cast<const float2*>(&xr[c]);
            vals[2 * i] = v.x;
            vals[2 * i + 1] = v.y;
        } else {
            ushort2 u = *reinterpret_cast<const ushort2*>(&xr[c]);
            union { unsigned short us; __hip_bfloat16 h; } a, b2;
            a.us = u.x; b2.us = u.y;
            vals[2 * i] = __bfloat162float(a.h);
            vals[2 * i + 1] = __bfloat162float(b2.h);
        }
        s += vals[2 * i] + vals[2 * i + 1];
    }
#pragma unroll
    for (int off = 1; off < 64; off <<= 1) s += __shfl_xor(s, off, 64);
    float mu = s * (1.f / E_DIM);
    float vv = 0.f;
#pragma unroll
    for (int i = 0; i < 6; i++) {
        float d = vals[i] - mu;
        vv += d * d;
    }
#pragma unroll
    for (int off = 1; off < 64; off <<= 1) vv += __shfl_xor(vv, off, 64);
    float rstd = rsqrtf(vv * (1.f / E_DIM) + 1e-5f);
#pragma unroll
    for (int i = 0; i < 3; i++) {
        int c = i * 128 + 2 * lane;
        float2 gv = *reinterpret_cast<const float2*>(&g[c]);
        float2 bv = *reinterpret_cast<const float2*>(&bta[c]);
        union { ushort2 u; struct { __hip_bfloat16 a, b; } h; } o2;
        o2.h.a = __float2bfloat16((vals[2 * i] - mu) * rstd * gv.x + bv.x);
        o2.h.b = __float2bfloat16((vals[2 * i + 1] - mu) * rstd * gv.y + bv.y);
        *reinterpret_cast<ushort2*>(&out[(size_t)row * E_DIM + c]) = o2.u;
    }
}

// ---------------------------------------------------------------------------
// Pipelined GEMM (round-9 structure): C = A[M][K] @ BT[N][K]^T, bf16, f32 acc.
// NW=8: BM=256, 512 thr, 72KB LDS, 2 blocks/CU. NW=4: BM=128, 256 thr, 48KB,
// 3 blocks/CU. BN=128, BK=32, triple-buffered, counted vmcnt, raw s_barrier,
// T5 setprio. Paired-row 128B-line LDS swizzle (zero bank conflicts).
// EPI: 0 = bf16 out; 2 = +bias relu -> bf16; 3 = +bias + f32 resid -> bf16;
//      4 = +bias + bf16 resid -> f32 out.
// ---------------------------------------------------------------------------
template <int EPI, int NW>
__global__ __launch_bounds__(NW * 64, NW == 8 ? 4 : 3) void gemm_kernel(
    const __hip_bfloat16* __restrict__ A, const __hip_bfloat16* __restrict__ BT,
    const float* __restrict__ bias, const void* __restrict__ resid,
    void* __restrict__ outp, int M, int N, int K) {
    constexpr int BM = NW * 32;
    constexpr int T = NW * 64;
    constexpr int BUF = (BM + 128) * 32;
    __shared__ __hip_bfloat16 lds[3 * BUF];
    const int t = threadIdx.x;
    const int w = t >> 6, lane = t & 63;
    const int l16 = lane & 15, lhi = lane >> 4;
    const int wm = w >> 1, wn = w & 1;

    const int nwg = gridDim.x;
    const int bid = blockIdx.x;
    const int cpx = nwg >> 3;
    const int swz = (bid & 7) * cpx + (bid >> 3);
    const int nb = N >> 7;
    const int m0 = (swz / nb) * BM;
    const int n0 = (swz % nb) * 128;

    const int ql = (t & 7) ^ ((t >> 3) & 7);
    const int sr = 2 * (t >> 3) + (ql >> 2);
    const int scol = (ql & 3) * 8;
    const __hip_bfloat16* pa0 = A + (size_t)(m0 + sr) * K + scol;
    const __hip_bfloat16* pa1 = pa0 + (size_t)(T / 4) * K;
    const __hip_bfloat16* pb0 = BT + (size_t)(n0 + sr) * K + scol;
    const __hip_bfloat16* pb1 = pb0 + (size_t)(T / 4) * K;
    const int dstA = t * 8;

    int aoff[4], boff[4];
#pragma unroll
    for (int mr = 0; mr < 4; mr++) {
        int R = wm * 64 + mr * 16 + l16;
        int L = R >> 1;
        int q = (((R & 1) << 2) | lhi) ^ (L & 7);
        aoff[mr] = L * 64 + q * 8;
    }
#pragma unroll
    for (int nr = 0; nr < 4; nr++) {
        int R = wn * 64 + nr * 16 + l16;
        int L = R >> 1;
        int q = (((R & 1) << 2) | lhi) ^ (L & 7);
        boff[nr] = BM * 32 + L * 64 + q * 8;
    }

    f32x4 acc[4][4] = {};
    const int nk = K >> 5;

#define STAGE(sbuf)                                                           \
    {                                                                         \
        __hip_bfloat16* sb_ = &lds[(sbuf) * BUF];                             \
        load_lds16(pa0, sb_ + dstA);                                          \
        load_lds16(pa1, sb_ + T * 8 + dstA);                                  \
        load_lds16(pb0, sb_ + BM * 32 + dstA);                                \
        if constexpr (NW == 4) load_lds16(pb1, sb_ + BM * 32 + T * 8 + dstA); \
        pa0 += 32;                                                            \
        pa1 += 32;                                                            \
        pb0 += 32;                                                            \
        if constexpr (NW == 4) pb1 += 32;                                     \
    }

    STAGE(0);
    STAGE(1);
    int rb = 0, sbx = 2;

    for (int kt = 0; kt < nk; kt++) {
        if (kt + 1 < nk) {
            if constexpr (NW == 8) asm volatile("s_waitcnt vmcnt(3)" ::: "memory");
            else                   asm volatile("s_waitcnt vmcnt(4)" ::: "memory");
        } else {
            asm volatile("s_waitcnt vmcnt(0)" ::: "memory");
        }
        __builtin_amdgcn_s_barrier();
        __builtin_amdgcn_sched_barrier(0);
        if (kt + 2 < nk) STAGE(sbx);
        const __hip_bfloat16* base = &lds[rb * BUF];
        bf16x8 af[4], bg[4];
#pragma unroll
        for (int mr = 0; mr < 4; mr++)
            af[mr] = *reinterpret_cast<const bf16x8*>(base + aoff[mr]);
#pragma unroll
        for (int nr = 0; nr < 4; nr++)
            bg[nr] = *reinterpret_cast<const bf16x8*>(base + boff[nr]);
        __builtin_amdgcn_s_setprio(1);
#pragma unroll
        for (int mr = 0; mr < 4; mr++)
#pragma unroll
            for (int nr = 0; nr < 4; nr++)
                acc[mr][nr] = MFMA_BF16(af[mr], bg[nr], acc[mr][nr]);
        __builtin_amdgcn_s_setprio(0);
        rb = rb == 2 ? 0 : rb + 1;
        sbx = sbx == 2 ? 0 : sbx + 1;
    }
#undef STAGE

    __hip_bfloat16* outb = (__hip_bfloat16*)outp;
    float* outf = (float*)outp;
#pragma unroll
    for (int mr = 0; mr < 4; mr++) {
#pragma unroll
        for (int nr = 0; nr < 4; nr++) {
            const int col = n0 + wn * 64 + nr * 16 + l16;
#pragma unroll
            for (int r = 0; r < 4; r++) {
                const int row = m0 + wm * 64 + mr * 16 + lhi * 4 + r;
                const size_t off = (size_t)row * N + col;
                float v = acc[mr][nr][r];
                if (EPI == 0) {
                    outb[off] = __float2bfloat16(v);
                } else if (EPI == 2) {
                    v += bias[col];
                    outb[off] = __float2bfloat16(v > 0.f ? v : 0.f);
                } else if (EPI == 3) {
                    v += bias[col] + ((const float*)resid)[off];
                    outb[off] = __float2bfloat16(v);
                } else {  // EPI == 4
                    v += bias[col] + to_f(((const __hip_bfloat16*)resid)[off]);
                    outf[off] = v;
                }
            }
        }
    }
}

// ---------------------------------------------------------------------------
// Causal attention, one block per (b,h), 256 thr = 4 waves, 2 blocks/CU.
// Wave w processes Q chunks {w, 7-w}. SWAPPED QK^T: s = MFMA(K, Q) so the
// lane holds 16 score values for ONE q-row -> in-lane softmax + 2 shfl_xor.
// ---------------------------------------------------------------------------
__global__ __launch_bounds__(256, 2) void attn_kernel(
    const __hip_bfloat16* __restrict__ qkv, __hip_bfloat16* __restrict__ o) {
    __shared__ __hip_bfloat16 Ks[T_SEQ * 64];    // 32 KB
    __shared__ __hip_bfloat16 VTs[64 * 256];     // 32 KB
    __shared__ __hip_bfloat16 Ps[4 * 2048];      // 16 KB

    const int bh = blockIdx.x;
    const int b = bh / H_HEADS, h = bh - b * H_HEADS;
    const int t = threadIdx.x;
    const int w = t >> 6, lane = t & 63;
    const int l16 = lane & 15, lhi = lane >> 4;
    const int l8 = l16 & 7;
    const size_t rbase = (size_t)b * T_SEQ;
    const int qoff = h * D_HEAD, koff = E_DIM + h * D_HEAD, voff = 2 * E_DIM + h * D_HEAD;
    const float qscale = 0.051031036307982884f * 1.4426950408889634f;

#pragma unroll
    for (int i = 0; i < 8; i++) {
        int idx = i * 256 + t;
        int r = idx >> 3;
        int c8 = idx & 7;
        load_lds16(qkv + (rbase + r) * QKV_LD + koff + ((c8 ^ (r & 7)) << 3),
                   &Ks[idx * 8]);
    }
#pragma unroll
    for (int i = 0; i < 8; i++) {
        int idx = i * 256 + t;
        int r = idx >> 3, d0 = (idx & 7) * 8;
        uint4 val = *reinterpret_cast<const uint4*>(qkv + (rbase + r) * QKV_LD + voff + d0);
        const __hip_bfloat16* p8 = reinterpret_cast<const __hip_bfloat16*>(&val);
        int slot = r >> 3, rin = r & 7;
#pragma unroll
        for (int j = 0; j < 8; j++) {
            int d = d0 + j;
            VTs[d * 256 + ((slot ^ (d & 7)) << 3) + rin] = p8[j];
        }
    }
    __syncthreads();

#pragma unroll
    for (int cp = 0; cp < 2; cp++) {
        const int c = cp ? 7 - w : w;
        bf16x8 qf[2][2];
#pragma unroll
        for (int mr = 0; mr < 2; mr++)
#pragma unroll
            for (int kk = 0; kk < 2; kk++)
                qf[mr][kk] = *reinterpret_cast<const bf16x8*>(
                    qkv + (rbase + c * 32 + mr * 16 + l16) * QKV_LD + qoff + kk * 32 + lhi * 8);

        float mstate[2] = {-1e30f, -1e30f};
        float lstate[2] = {0.f, 0.f};
        f32x4 oacc[2][4] = {};

        const int njt = (c >> 1) + 1;
        for (int jt = 0; jt < njt; jt++) {
            const bool diag = (jt == (c >> 1));
            f32x4 s[2][4] = {};
#pragma unroll
            for (int kk = 0; kk < 2; kk++) {
                bf16x8 kf[4];
#pragma unroll
                for (int nr = 0; nr < 4; nr++) {
                    int R = jt * 64 + nr * 16 + l16;
                    kf[nr] = *reinterpret_cast<const bf16x8*>(
                        &Ks[R * 64 + (((kk << 2) + lhi) ^ l8) * 8]);
                }
#pragma unroll
                for (int mr = 0; mr < 2; mr++)
#pragma unroll
                    for (int nr = 0; nr < 4; nr++)
                        s[mr][nr] = MFMA_BF16(kf[nr], qf[mr][kk], s[mr][nr]);
            }
#pragma unroll
            for (int mr = 0; mr < 2; mr++) {
                const int qrow = c * 32 + mr * 16 + l16;
                float pv[4][4];
                float mx = -1e30f;
#pragma unroll
                for (int nr = 0; nr < 4; nr++)
#pragma unroll
                    for (int r = 0; r < 4; r++) {
                        int kcol = jt * 64 + nr * 16 + lhi * 4 + r;
                        float val = s[mr][nr][r] * qscale;
                        if (diag && kcol > qrow) val = -1e30f;
                        pv[nr][r] = val;
                        mx = fmaxf(mx, val);
                    }
                mx = fmaxf(mx, __shfl_xor(mx, 16, 64));
                mx = fmaxf(mx, __shfl_xor(mx, 32, 64));
                float mold = mstate[mr];
                float mnew = fmaxf(mold, mx);
                float corr = exp2f(mold - mnew);
                float psum = 0.f;
#pragma unroll
                for (int nr = 0; nr < 4; nr++)
#pragma unroll
                    for (int r = 0; r < 4; r++) {
                        float p = exp2f(pv[nr][r] - mnew);
                        pv[nr][r] = p;
                        psum += p;
                    }
                psum += __shfl_xor(psum, 16, 64);
                psum += __shfl_xor(psum, 32, 64);
                lstate[mr] = lstate[mr] * corr + psum;
                mstate[mr] = mnew;
#pragma unroll
                for (int r = 0; r < 4; r++) {
                    float cT = __shfl(corr, lhi * 4 + r, 64);
#pragma unroll
                    for (int dr = 0; dr < 4; dr++) oacc[mr][dr][r] *= cT;
                }
#pragma unroll
                for (int nr = 0; nr < 4; nr++)
#pragma unroll
                    for (int r = 0; r < 4; r++) {
                        int q = mr * 16 + l16;
                        int kc = nr * 16 + lhi * 4 + r;
                        Ps[w * 2048 + q * 64 + (((kc >> 3) ^ (q & 7)) << 3) + (kc & 7)] =
                            __float2bfloat16(pv[nr][r]);
                    }
            }
#pragma unroll
            for (int kk = 0; kk < 2; kk++) {
                bf16x8 pa[2], vbf[4];
#pragma unroll
                for (int mr = 0; mr < 2; mr++) {
                    int row = mr * 16 + l16;
                    pa[mr] = *reinterpret_cast<const bf16x8*>(
                        &Ps[w * 2048 + row * 64 + (((kk << 2) + lhi) ^ l8) * 8]);
                }
#pragma unroll
                for (int dr = 0; dr < 4; dr++) {
                    int d = dr * 16 + l16;
                    int slot = (jt << 3) + (kk << 2) + lhi;
                    vbf[dr] = *reinterpret_cast<const bf16x8*>(
                        &VTs[d * 256 + ((slot ^ l8) << 3)]);
                }
#pragma unroll
                for (int mr = 0; mr < 2; mr++)
#pragma unroll
                    for (int dr = 0; dr < 4; dr++)
                        oacc[mr][dr] = MFMA_BF16(pa[mr], vbf[dr], oacc[mr][dr]);
            }
        }

#pragma unroll
        for (int mr = 0; mr < 2; mr++) {
            float rl = 1.f / lstate[mr];
#pragma unroll
            for (int r = 0; r < 4; r++) {
                float rlT = __shfl(rl, lhi * 4 + r, 64);
                int row = c * 32 + mr * 16 + lhi * 4 + r;
#pragma unroll
                for (int dr = 0; dr < 4; dr++)
                    o[(rbase + row) * E_DIM + h * D_HEAD + dr * 16 + l16] =
                        __float2bfloat16(oacc[mr][dr][r] * rlT);
            }
        }
    }
}

// ---------------------------------------------------------------------------
extern "C" void kernel_launch(void* const* d_in, const int* in_sizes, int n_in,
                              void* d_out, int out_size, void* d_ws, size_t ws_size,
                              hipStream_t stream) {
    const float* x      = (const float*)d_in[0];
    const float* wq     = (const float*)d_in[1];
    const float* wk     = (const float*)d_in[2];
    const float* wv     = (const float*)d_in[3];
    const float* w_proj = (const float*)d_in[4];
    const float* b_proj = (const float*)d_in[5];
    const float* w1     = (const float*)d_in[6];
    const float* b1     = (const float*)d_in[7];
    const float* w2     = (const float*)d_in[8];
    const float* b2     = (const float*)d_in[9];
    const float* g1     = (const float*)d_in[10];
    const float* bt1    = (const float*)d_in[11];
    const float* g2     = (const float*)d_in[12];
    const float* bt2    = (const float*)d_in[13];
    float* out = (float*)d_out;

    char* ws = (char*)d_ws;
    size_t off = 0;
    auto alloc = [&](size_t bytes) {
        void* p = ws + off;
        off += (bytes + 255) & ~(size_t)255;
        return p;
    };
    const size_t wElems = E_DIM * E_DIM;
    const size_t fElems = E_DIM * FF_DIM;
    const size_t actElems = (size_t)NROWS * E_DIM;
    __hip_bfloat16* wqkvT = (__hip_bfloat16*)alloc(3 * wElems * 2);  // [1152][384]
    __hip_bfloat16* wpT   = (__hip_bfloat16*)alloc(wElems * 2);
    __hip_bfloat16* w1T   = (__hip_bfloat16*)alloc(fElems * 2);
    __hip_bfloat16* w2T   = (__hip_bfloat16*)alloc(fElems * 2);
    __hip_bfloat16* lnb   = (__hip_bfloat16*)alloc(actElems * 2);      // ln1 / ln2
    __hip_bfloat16* x2b   = (__hip_bfloat16*)alloc(actElems * 2);      // residual (bf16)
    __hip_bfloat16* qkv   = (__hip_bfloat16*)alloc(3 * actElems * 2);  // [32768][1152]
    __hip_bfloat16* ab    = (__hip_bfloat16*)alloc(actElems * 2);      // attn out
    __hip_bfloat16* h1    = qkv;  // FFN hidden (96MB) reuses qkv+ab space

    // 1+2) weights -> bf16 transposed AND ln1, one launch
    prep_kernel<<<TCAST_BLOCKS + NROWS / 4, 256, 0, stream>>>(
        x, g1, bt1, lnb, wq, wk, wv, w_proj, w1, w2, wqkvT, wpT, w1T, w2T);

    // 3) fused qkv: [32768][1152]
    gemm_kernel<0, 8><<<(NROWS / 256) * (QKV_LD / 128), 512, 0, stream>>>(
        lnb, wqkvT, nullptr, nullptr, qkv, NROWS, QKV_LD, E_DIM);

    // 4) attention
    attn_kernel<<<B_BATCH * H_HEADS, 256, 0, stream>>>(qkv, ab);

    // 5) x2b = bf16(x + attn @ w_proj + b_proj)
    gemm_kernel<3, 4><<<(NROWS / 128) * (E_DIM / 128), 256, 0, stream>>>(
        ab, wpT, b_proj, x, x2b, NROWS, E_DIM, E_DIM);

    // 6) ln2 (bf16 input)
    ln_kernel<__hip_bfloat16><<<NROWS / 4, 256, 0, stream>>>(x2b, g2, bt2, lnb);

    // 7) h1 = relu(ln2 @ w1 + b1)
    gemm_kernel<2, 8><<<(NROWS / 256) * (FF_DIM / 128), 512, 0, stream>>>(
        lnb, w1T, b1, nullptr, h1, NROWS, FF_DIM, E_DIM);

    // 8) out = x2b + h1 @ w2 + b2  (f32 out)
    gemm_kernel<4, 4><<<(NROWS / 128) * (E_DIM / 128), 256, 0, stream>>>(
        h1, w2T, b2, x2b, out, NROWS, E_DIM, FF_DIM);
}